// Round 5
// baseline (198.382 us; speedup 1.0000x reference)
//
#include <hip/hip_runtime.h>
#include <hip/hip_bf16.h>

// Temporal_Aggregation — MFMA bf16, fp32 I/O (MI355X gfx950). Round 14.
//
// Folded math (validated rounds 4-8):
//   Wbig[o][j=k*64+i] = sum_c Wlin[o][c]*Wconv[c][i][0][k]   (bf16 in ws)
//   z[t][o]  = sum_j Vp[t+(j>>6)][j&63] * Wbig[o][j]
//   out[t][o] = relu( z[t-1]+z[t]+z[t+1] (clipped) + m_t*biasC[o] + blin[o] )
//
// Round-14 = round-13 (unmeasured: acquisition timeout) resubmitted, with a
// running source pointer instead of a per-iteration 64-bit tile multiply.
// Theory under test: r11/r12 sat at ~59us / 2.5 TB/s with all pipes idle ->
// burst-and-drain MLP starvation (reads in flight only during each block's
// short staging window). Persistent blocks (grid 1024, 4 tiles each) with
// register-pipelined staging keep 6 KB/wave outstanding under the whole
// K-loop + epilogue: 16 waves/CU x 6 KB ~= 96 KB/CU >> 22 KB Little's-law
// requirement at ~900ns latency.

typedef __attribute__((ext_vector_type(8))) short short8;
typedef __attribute__((ext_vector_type(8))) __bf16 bf16x8;
typedef __attribute__((ext_vector_type(4))) float f4;

#define R_ROWS 4                 // rows per tile
#define NBLOCKS 1024
#define TILES_PER_BLOCK 4        // 1024 * 4 * 4 rows = 16384 rows
#define VP_STRIDE 72             // 64 + 8 pad shorts
#define V_ROW_ELEMS (26 * VP_STRIDE)   // 1872 shorts (pad + 24 + pad)

__device__ __forceinline__ unsigned short f2bfu(float f) {
    return __bfloat16_as_ushort(__float2bfloat16(f));
}

// ---- Kernel 1: fold conv+linear weights -------------------------------------
// ws bytes: [0,24576) Wbig bf16[64][192]; [24576,24832) biasC f32[64];
//           [24832,25088) blinF f32[64]
__global__ void prep_kernel(const float* __restrict__ Wconv,
                            const float* __restrict__ bconv,
                            const float* __restrict__ Wlin,
                            const float* __restrict__ blin,
                            __hip_bfloat16* __restrict__ wbig,
                            float* __restrict__ biasC,
                            float* __restrict__ blinF) {
    __shared__ float Wl[4096];
    const int tid = threadIdx.x;
    for (int c = tid; c < 4096; c += 256) Wl[c] = Wlin[c];
    __syncthreads();
    int idx = blockIdx.x * 256 + tid;
    if (idx < 64 * 192) {
        int o = idx / 192;
        int j = idx - o * 192;
        int k = j >> 6;
        int i = j & 63;
        float acc = 0.0f;
        for (int c = 0; c < 64; ++c)
            acc += Wl[o * 64 + c] * Wconv[c * 192 + i * 3 + k];
        wbig[o * 192 + j] = __float2bfloat16(acc);
    } else if (idx < 64 * 192 + 64) {
        int o = idx - 64 * 192;
        float acc = 0.0f;
        for (int c = 0; c < 64; ++c)
            acc += Wl[o * 64 + c] * bconv[c];
        biasC[o] = acc;
    } else if (idx < 64 * 192 + 128) {
        int o = idx - (64 * 192 + 64);
        blinF[o] = blin[o];
    }
}

// ---- Kernel 2: fused conv-GEMM + band sum + bias + relu ---------------------
__global__ __launch_bounds__(256, 5) void fused_kernel(
    const float* __restrict__ value,
    const __hip_bfloat16* __restrict__ wbig,
    const float* __restrict__ biasC,
    const float* __restrict__ blinF,
    float* __restrict__ out) {
    __shared__ __align__(16) short Vlds[R_ROWS * V_ROW_ELEMS];   // 14976 B

    const int tid = threadIdx.x;
    const int wave = tid >> 6;            // = N-tile index (16 o-columns)
    const int lane = tid & 63;
    const int lane15 = lane & 15;
    const int quad = lane >> 4;

    // ---- loop-invariant state ----
    const short* wsrc = (const short*)wbig;
    const int k0 = quad * 8;
    bf16x8 breg[6];
    #pragma unroll
    for (int ks = 0; ks < 6; ++ks)
        breg[ks] = __builtin_bit_cast(bf16x8,
            *(const short8*)(wsrc + (wave * 16 + lane15) * 192 + ks * 32 + k0));

    const int o = wave * 16 + lane15;
    const float bc = biasC[o];
    const float bl = blinF[o];
    const float b3 = 3.0f * bc + bl;
    const float b2 = 2.0f * bc + bl;
    const int srcP = (lane + 48) & 63;    // receive from quad-1
    const int srcN = (lane + 16) & 63;    // receive from quad+1

    const int sr = tid >> 6;              // row in tile 0..3 (== wave)
    const int tq = (tid >> 4) & 3;        // t mod 4 group
    const int d4 = (tid & 15) << 2;       // float4 column

    int aoff[6];
    #pragma unroll
    for (int mt = 0; mt < 6; ++mt) {
        int m = mt * 16 + lane15;          // GEMM row, m = r*24 + s
        int r = m / 24;
        int s = m - r * 24;
        aoff[mt] = r * V_ROW_ELEMS + s * VP_STRIDE;
    }

    if (tid < 64) {                        // zero pad rows 0 and 25 (once)
        int r = tid >> 4;                  // 0..3
        int which = (tid >> 3) & 1;
        int d8 = (tid & 7) << 3;
        uint4 z; z.x = 0; z.y = 0; z.z = 0; z.w = 0;
        *(uint4*)(Vlds + r * V_ROW_ELEMS + which * (25 * VP_STRIDE) + d8) = z;
    }

    // ---- prologue: issue tile-0 loads; running pointer (stride 6 MB) ----
    const float* vsrc = value + (long)blockIdx.x * (R_ROWS * 1536)
                        + sr * 1536 + tq * 64 + d4;
    f4 pre[6];
    #pragma unroll
    for (int j = 0; j < 6; ++j)
        pre[j] = *(const f4*)(vsrc + j * 256);   // t = 4j+tq
    vsrc += (long)NBLOCKS * (R_ROWS * 1536);

    short* const lbase = Vlds + sr * V_ROW_ELEMS + (tq + 1) * VP_STRIDE + d4;
    float* pbase = out + (long)blockIdx.x * (R_ROWS * 1536) + quad * 256 + o;

    #pragma unroll
    for (int it = 0; it < TILES_PER_BLOCK; ++it) {
        if (it) __syncthreads();           // previous K-loop readers done
        // ---- ds_write current tile (vmcnt waits happen here) ----
        #pragma unroll
        for (int j = 0; j < 6; ++j) {
            ushort4 u;
            u.x = f2bfu(pre[j].x); u.y = f2bfu(pre[j].y);
            u.z = f2bfu(pre[j].z); u.w = f2bfu(pre[j].w);
            *(ushort4*)(lbase + j * (4 * VP_STRIDE)) = u;
        }
        // ---- issue next tile's loads: in flight under K-loop + epilogue ----
        if (it + 1 < TILES_PER_BLOCK) {
            #pragma unroll
            for (int j = 0; j < 6; ++j)
                pre[j] = *(const f4*)(vsrc + j * 256);
            vsrc += (long)NBLOCKS * (R_ROWS * 1536);
        }
        __syncthreads();                   // LDS writes visible

        // ---- K-loop: 6 M-tiles x this wave's N-tile, K=192 ----
        f4 acc[6];
        #pragma unroll
        for (int mt = 0; mt < 6; ++mt) {
            f4 zz = {0.f, 0.f, 0.f, 0.f};
            acc[mt] = zz;
        }
        #pragma unroll
        for (int ks = 0; ks < 6; ++ks) {
            int k = ks * 32 + k0;
            int ka = ((k >> 6) * VP_STRIDE) + (k & 63);
            #pragma unroll
            for (int mt = 0; mt < 6; ++mt) {
                bf16x8 a = __builtin_bit_cast(bf16x8,
                    *(const short8*)(Vlds + aoff[mt] + ka));
                acc[mt] = __builtin_amdgcn_mfma_f32_16x16x32_bf16(
                    a, breg[ks], acc[mt], 0, 0, 0);
            }
        }

        // ---- epilogue: wave-local band sum, bias, relu, store ----
        // C/D layout: col = lane&15, row16 = quad*4 + i  [m89]
        // out offset = tile*6144 + rowq*64 + o, rowq = mt*16 + quad*4 + i
        // t==0 only at i==0; t==23 only at i==3 (rowq === i mod 4).
        #pragma unroll
        for (int mt = 0; mt < 6; ++mt) {
            const int mtp = (mt > 0) ? mt - 1 : 0;
            const int mtn = (mt < 5) ? mt + 1 : 5;
            float sendP = (quad == 3) ? acc[mtp][3] : acc[mt][3];
            float sendN = (quad == 0) ? acc[mtn][0] : acc[mt][0];
            float prev0 = __shfl(sendP, srcP, 64);
            float next3 = __shfl(sendN, srcN, 64);
            const int m3 = mt % 3;
            const bool t0  = (m3 == 0) ? (quad == 0)
                           : ((m3 == 1) ? (quad == 2) : false);
            const bool t23 = (m3 == 2) ? (quad == 3)
                           : ((m3 == 1) ? (quad == 1) : false);
            float s0 = acc[mt][0] + acc[mt][1] + (t0  ? b2 : (prev0 + b3));
            float s1 = acc[mt][0] + acc[mt][1] + acc[mt][2] + b3;
            float s2 = acc[mt][1] + acc[mt][2] + acc[mt][3] + b3;
            float s3 = acc[mt][2] + acc[mt][3] + (t23 ? b2 : (next3 + b3));
            float* p = pbase + mt * 1024;     // mt*16*64, compile-time
            p[0]   = fmaxf(s0, 0.0f);
            p[64]  = fmaxf(s1, 0.0f);
            p[128] = fmaxf(s2, 0.0f);
            p[192] = fmaxf(s3, 0.0f);
        }
        pbase += (long)NBLOCKS * (R_ROWS * 1536);
    }
}

extern "C" void kernel_launch(void* const* d_in, const int* in_sizes, int n_in,
                              void* d_out, int out_size, void* d_ws, size_t ws_size,
                              hipStream_t stream) {
    const float* value = (const float*)d_in[0];
    const float* Wconv = (const float*)d_in[1];
    const float* bconv = (const float*)d_in[2];
    const float* Wlin  = (const float*)d_in[3];
    const float* blin  = (const float*)d_in[4];
    float* out = (float*)d_out;

    __hip_bfloat16* wbig = (__hip_bfloat16*)d_ws;
    float* biasC = (float*)((char*)d_ws + 24576);
    float* blinF = (float*)((char*)d_ws + 24832);

    prep_kernel<<<49, 256, 0, stream>>>(Wconv, bconv, Wlin, blin, wbig, biasC, blinF);
    // 1024 persistent blocks x 4 tiles x 4 rows = 16384 rows
    fused_kernel<<<NBLOCKS, 256, 0, stream>>>(value, wbig, biasC, blinF, out);
}

// Round 16
// 195.415 us; speedup vs baseline: 1.0152x; 1.0152x over previous
//
#include <hip/hip_runtime.h>
#include <hip/hip_bf16.h>

// Temporal_Aggregation — MFMA bf16, fp32 I/O (MI355X gfx950). Round 25.
// (= Round-18..24 A/B probe, still unmeasured after 13 broker-side
//  acquisition timeouts; resubmitted unchanged — never mutate an unmeasured
//  experiment. Also the correct risk posture if the session ends unmeasured:
//  bounded regret vs r12 baseline, upside if the write-path theory holds.)
// WITHIN-RUN A/B: grid split into two serialized dispatches so ONE bench
// measures both epilogues under identical clocks (slots are scarce):
//   fused_old = r12 epilogue (shuffle band-sum, 24x 64-B partial-line
//               stores/wave) on rows 0..8191   — measured 58.7us baseline.
//   fused_new = r15 epilogue (Zlds transpose, 6x 1KB full-line
//               stores/wave) on rows 8192..16383 — write-path theory.
// Discriminator: per-dispatch WRITE_SIZE (old ~55 MB amplified vs new
// ~49.2 MB ideal) + dur_us delta.
//
// Folded math (validated rounds 4-8):
//   Wbig[o][j=k*64+i] = sum_c Wlin[o][c]*Wconv[c][i][0][k]   (bf16 in ws)
//   z[t][o]  = sum_j Vp[t+(j>>6)][j&63] * Wbig[o][j]
//   out[t][o] = relu( z[t-1]+z[t]+z[t+1] (clipped) + m_t*biasC[o] + blin[o] )

typedef __attribute__((ext_vector_type(8))) short short8;
typedef __attribute__((ext_vector_type(8))) __bf16 bf16x8;
typedef __attribute__((ext_vector_type(4))) float f4;

#define R_ROWS 4                 // rows per block
#define HALF_BLOCKS 2048         // blocks per dispatch (x4 rows = 8192 rows)
#define VP_STRIDE 72             // 64 + 8 pad shorts
#define V_ROW_ELEMS (26 * VP_STRIDE)   // 1872 shorts (pad + 24 + pad)
#define Z_STRIDE 68              // 64 + 4 pad floats (16B-aligned rows)

__device__ __forceinline__ unsigned short f2bfu(float f) {
    return __bfloat16_as_ushort(__float2bfloat16(f));
}

// ---- Kernel 1: fold conv+linear weights -------------------------------------
// ws bytes: [0,24576) Wbig bf16[64][192]; [24576,24832) biasC f32[64];
//           [24832,25088) blinF f32[64]
__global__ void prep_kernel(const float* __restrict__ Wconv,
                            const float* __restrict__ bconv,
                            const float* __restrict__ Wlin,
                            const float* __restrict__ blin,
                            __hip_bfloat16* __restrict__ wbig,
                            float* __restrict__ biasC,
                            float* __restrict__ blinF) {
    __shared__ float Wl[4096];
    const int tid = threadIdx.x;
    for (int c = tid; c < 4096; c += 256) Wl[c] = Wlin[c];
    __syncthreads();
    int idx = blockIdx.x * 256 + tid;
    if (idx < 64 * 192) {
        int o = idx / 192;
        int j = idx - o * 192;
        int k = j >> 6;
        int i = j & 63;
        float acc = 0.0f;
        for (int c = 0; c < 64; ++c)
            acc += Wl[o * 64 + c] * Wconv[c * 192 + i * 3 + k];
        wbig[o * 192 + j] = __float2bfloat16(acc);
    } else if (idx < 64 * 192 + 64) {
        int o = idx - 64 * 192;
        float acc = 0.0f;
        for (int c = 0; c < 64; ++c)
            acc += Wl[o * 64 + c] * bconv[c];
        biasC[o] = acc;
    } else if (idx < 64 * 192 + 128) {
        int o = idx - (64 * 192 + 64);
        blinF[o] = blin[o];
    }
}

// ---- Kernel 2a: r12 epilogue (partial-line stores) — rows 0..8191 -----------
__global__ __launch_bounds__(256, 6) void fused_old(
    const float* __restrict__ value,
    const __hip_bfloat16* __restrict__ wbig,
    const float* __restrict__ biasC,
    const float* __restrict__ blinF,
    float* __restrict__ out) {
    __shared__ __align__(16) short Vlds[R_ROWS * V_ROW_ELEMS];   // 14976 B

    const int tid = threadIdx.x;
    const int wave = tid >> 6;
    const int lane = tid & 63;
    const int lane15 = lane & 15;
    const int quad = lane >> 4;
    const long base_row = (long)blockIdx.x * R_ROWS;

    f4 pre[6];
    const int sr = tid >> 6;
    const int tq = (tid >> 4) & 3;
    const int d4 = (tid & 15) << 2;
    {
        const float* vrow = value + base_row * 1536 + sr * 1536 + tq * 64 + d4;
        #pragma unroll
        for (int j = 0; j < 6; ++j)
            pre[j] = *(const f4*)(vrow + j * 256);
    }

    const short* wsrc = (const short*)wbig;
    const int k0 = quad * 8;
    bf16x8 breg[6];
    #pragma unroll
    for (int ks = 0; ks < 6; ++ks)
        breg[ks] = __builtin_bit_cast(bf16x8,
            *(const short8*)(wsrc + (wave * 16 + lane15) * 192 + ks * 32 + k0));

    const int o = wave * 16 + lane15;
    const float bc = biasC[o];
    const float bl = blinF[o];

    if (tid < 64) {
        int r = tid >> 4;
        int which = (tid >> 3) & 1;
        int d8 = (tid & 7) << 3;
        uint4 z; z.x = 0; z.y = 0; z.z = 0; z.w = 0;
        *(uint4*)(Vlds + r * V_ROW_ELEMS + which * (25 * VP_STRIDE) + d8) = z;
    }
    {
        short* lbase = Vlds + sr * V_ROW_ELEMS + (tq + 1) * VP_STRIDE + d4;
        #pragma unroll
        for (int j = 0; j < 6; ++j) {
            ushort4 u;
            u.x = f2bfu(pre[j].x); u.y = f2bfu(pre[j].y);
            u.z = f2bfu(pre[j].z); u.w = f2bfu(pre[j].w);
            *(ushort4*)(lbase + j * (4 * VP_STRIDE)) = u;
        }
    }
    __syncthreads();

    int aoff[6];
    #pragma unroll
    for (int mt = 0; mt < 6; ++mt) {
        int m = mt * 16 + lane15;
        int r = m / 24;
        int s = m - r * 24;
        aoff[mt] = r * V_ROW_ELEMS + s * VP_STRIDE;
    }
    f4 acc[6];
    #pragma unroll
    for (int mt = 0; mt < 6; ++mt) {
        f4 zz = {0.f, 0.f, 0.f, 0.f};
        acc[mt] = zz;
    }
    #pragma unroll
    for (int ks = 0; ks < 6; ++ks) {
        int k = ks * 32 + k0;
        int ka = ((k >> 6) * VP_STRIDE) + (k & 63);
        #pragma unroll
        for (int mt = 0; mt < 6; ++mt) {
            bf16x8 a = __builtin_bit_cast(bf16x8,
                *(const short8*)(Vlds + aoff[mt] + ka));
            acc[mt] = __builtin_amdgcn_mfma_f32_16x16x32_bf16(
                a, breg[ks], acc[mt], 0, 0, 0);
        }
    }

    const float b3 = 3.0f * bc + bl;
    const float b2 = 2.0f * bc + bl;
    const int srcP = (lane + 48) & 63;
    const int srcN = (lane + 16) & 63;
    float* pbase = out + base_row * 1536 + quad * 256 + o;
    #pragma unroll
    for (int mt = 0; mt < 6; ++mt) {
        const int mtp = (mt > 0) ? mt - 1 : 0;
        const int mtn = (mt < 5) ? mt + 1 : 5;
        float sendP = (quad == 3) ? acc[mtp][3] : acc[mt][3];
        float sendN = (quad == 0) ? acc[mtn][0] : acc[mt][0];
        float prev0 = __shfl(sendP, srcP, 64);
        float next3 = __shfl(sendN, srcN, 64);
        const int m3 = mt % 3;
        const bool t0  = (m3 == 0) ? (quad == 0)
                       : ((m3 == 1) ? (quad == 2) : false);
        const bool t23 = (m3 == 2) ? (quad == 3)
                       : ((m3 == 1) ? (quad == 1) : false);
        float s0 = acc[mt][0] + acc[mt][1] + (t0  ? b2 : (prev0 + b3));
        float s1 = acc[mt][0] + acc[mt][1] + acc[mt][2] + b3;
        float s2 = acc[mt][1] + acc[mt][2] + acc[mt][3] + b3;
        float s3 = acc[mt][2] + acc[mt][3] + (t23 ? b2 : (next3 + b3));
        float* p = pbase + mt * 1024;
        p[0]   = fmaxf(s0, 0.0f);
        p[64]  = fmaxf(s1, 0.0f);
        p[128] = fmaxf(s2, 0.0f);
        p[192] = fmaxf(s3, 0.0f);
    }
}

// ---- Kernel 2b: r15 epilogue (full-line stores) — rows 8192..16383 ----------
__global__ __launch_bounds__(256, 6) void fused_new(
    const float* __restrict__ value,
    const __hip_bfloat16* __restrict__ wbig,
    const float* __restrict__ biasC,
    const float* __restrict__ blinF,
    float* __restrict__ out) {
    __shared__ __align__(16) float LDS[96 * Z_STRIDE];           // 26112 B
    short* const Vlds = (short*)LDS;
    float* const Zlds = LDS;

    const int tid = threadIdx.x;
    const int wave = tid >> 6;
    const int lane = tid & 63;
    const int lane15 = lane & 15;
    const int quad = lane >> 4;
    const long base_row = (long)(blockIdx.x + HALF_BLOCKS) * R_ROWS;

    f4 pre[6];
    const int sr = tid >> 6;
    const int tq = (tid >> 4) & 3;
    const int d4 = (tid & 15) << 2;
    {
        const float* vrow = value + base_row * 1536 + sr * 1536 + tq * 64 + d4;
        #pragma unroll
        for (int j = 0; j < 6; ++j)
            pre[j] = *(const f4*)(vrow + j * 256);
    }

    const short* wsrc = (const short*)wbig;
    const int k0 = quad * 8;
    bf16x8 breg[6];
    #pragma unroll
    for (int ks = 0; ks < 6; ++ks)
        breg[ks] = __builtin_bit_cast(bf16x8,
            *(const short8*)(wsrc + (wave * 16 + lane15) * 192 + ks * 32 + k0));

    const f4 bc4 = *(const f4*)(biasC + lane15 * 4);
    const f4 bl4 = *(const f4*)(blinF + lane15 * 4);
    f4 b3v, b2v;
    #pragma unroll
    for (int c = 0; c < 4; ++c) {
        b3v[c] = 3.0f * bc4[c] + bl4[c];
        b2v[c] = 2.0f * bc4[c] + bl4[c];
    }

    if (tid < 64) {
        int r = tid >> 4;
        int which = (tid >> 3) & 1;
        int d8 = (tid & 7) << 3;
        uint4 z; z.x = 0; z.y = 0; z.z = 0; z.w = 0;
        *(uint4*)(Vlds + r * V_ROW_ELEMS + which * (25 * VP_STRIDE) + d8) = z;
    }
    {
        short* lbase = Vlds + sr * V_ROW_ELEMS + (tq + 1) * VP_STRIDE + d4;
        #pragma unroll
        for (int j = 0; j < 6; ++j) {
            ushort4 u;
            u.x = f2bfu(pre[j].x); u.y = f2bfu(pre[j].y);
            u.z = f2bfu(pre[j].z); u.w = f2bfu(pre[j].w);
            *(ushort4*)(lbase + j * (4 * VP_STRIDE)) = u;
        }
    }
    __syncthreads();                       // barrier 1: staging visible

    int aoff[6];
    #pragma unroll
    for (int mt = 0; mt < 6; ++mt) {
        int m = mt * 16 + lane15;
        int r = m / 24;
        int s = m - r * 24;
        aoff[mt] = r * V_ROW_ELEMS + s * VP_STRIDE;
    }
    f4 acc[6];
    #pragma unroll
    for (int mt = 0; mt < 6; ++mt) {
        f4 zz = {0.f, 0.f, 0.f, 0.f};
        acc[mt] = zz;
    }
    #pragma unroll
    for (int ks = 0; ks < 6; ++ks) {
        int k = ks * 32 + k0;
        int ka = ((k >> 6) * VP_STRIDE) + (k & 63);
        #pragma unroll
        for (int mt = 0; mt < 6; ++mt) {
            bf16x8 a = __builtin_bit_cast(bf16x8,
                *(const short8*)(Vlds + aoff[mt] + ka));
            acc[mt] = __builtin_amdgcn_mfma_f32_16x16x32_bf16(
                a, breg[ks], acc[mt], 0, 0, 0);
        }
    }
    __syncthreads();                       // barrier 2: Vlds dead -> Zlds

    // dump raw z to Zlds[96][68]; z row = mt*16 + quad*4 + i, col = o
    {
        float* zb = Zlds + (quad * 4) * Z_STRIDE + wave * 16 + lane15;
        #pragma unroll
        for (int mt = 0; mt < 6; ++mt) {
            #pragma unroll
            for (int i = 0; i < 4; ++i)
                zb[(mt * 16 + i) * Z_STRIDE] = acc[mt][i];
        }
    }
    __syncthreads();                       // barrier 3: z visible

    // band sum + bias + relu; wave w owns z-rows 24w..24w+23 (t = 0..23);
    // one store instruction = 64 lanes x 16 B = 1 KB contiguous.
    {
        const int sub = quad;
        float* obase = out + base_row * 1536 + ((long)wave * 24) * 64
                       + lane15 * 4;
        #pragma unroll
        for (int it = 0; it < 6; ++it) {
            const int t = it * 4 + sub;            // 0..23
            const int rowL = wave * 24 + t;        // z row 0..95
            const bool att0 = (t == 0);
            const bool att23 = (t == 23);
            const int rp = att0 ? rowL : rowL - 1;
            const int rn = att23 ? rowL : rowL + 1;
            f4 zc = *(const f4*)(Zlds + rowL * Z_STRIDE + lane15 * 4);
            f4 zp = *(const f4*)(Zlds + rp * Z_STRIDE + lane15 * 4);
            f4 zn = *(const f4*)(Zlds + rn * Z_STRIDE + lane15 * 4);
            f4 s;
            #pragma unroll
            for (int c = 0; c < 4; ++c) {
                float v = zc[c];
                if (!att0)  v += zp[c];
                if (!att23) v += zn[c];
                v += (att0 || att23) ? b2v[c] : b3v[c];
                s[c] = fmaxf(v, 0.0f);
            }
            *(f4*)(obase + (it * 4 + sub) * 64) = s;
        }
    }
}

extern "C" void kernel_launch(void* const* d_in, const int* in_sizes, int n_in,
                              void* d_out, int out_size, void* d_ws, size_t ws_size,
                              hipStream_t stream) {
    const float* value = (const float*)d_in[0];
    const float* Wconv = (const float*)d_in[1];
    const float* bconv = (const float*)d_in[2];
    const float* Wlin  = (const float*)d_in[3];
    const float* blin  = (const float*)d_in[4];
    float* out = (float*)d_out;

    __hip_bfloat16* wbig = (__hip_bfloat16*)d_ws;
    float* biasC = (float*)((char*)d_ws + 24576);
    float* blinF = (float*)((char*)d_ws + 24832);

    prep_kernel<<<49, 256, 0, stream>>>(Wconv, bconv, Wlin, blin, wbig, biasC, blinF);
    // A/B split: rows 0..8191 old epilogue, rows 8192..16383 new epilogue.
    fused_old<<<HALF_BLOCKS, 256, 0, stream>>>(value, wbig, biasC, blinF, out);
    fused_new<<<HALF_BLOCKS, 256, 0, stream>>>(value, wbig, biasC, blinF, out);
}

// Round 17
// 187.968 us; speedup vs baseline: 1.0554x; 1.0396x over previous
//
#include <hip/hip_runtime.h>
#include <hip/hip_bf16.h>

// Temporal_Aggregation — MFMA bf16, fp32 I/O (MI355X gfx950). Round 26.
//
// r16's A/B finally ran (passed, absmax unchanged): both halves < 58 µs so
// the duration-sorted top-5 showed only poison fills — per-dispatch A/B
// counters are unobtainable on this harness for any kernel faster than the
// ~58.5 µs fills. Only readable signal = total dur_us (noise ±5 µs).
// => Commit full grid to the r15 full-line-store epilogue (correctness-
// proven on rows 8192..16383 in r16). Write-path theory predicts fused
// 58.7 -> ~45 µs, total ~178-185. Null => total ~190-197, store path
// exonerated, next pivot = no-LDS/no-barrier per-lane A-fragment kernel.
//
// Folded math (validated rounds 4-8):
//   Wbig[o][j=k*64+i] = sum_c Wlin[o][c]*Wconv[c][i][0][k]   (bf16 in ws)
//   z[t][o]  = sum_j Vp[t+(j>>6)][j&63] * Wbig[o][j]
//   out[t][o] = relu( z[t-1]+z[t]+z[t+1] (clipped) + m_t*biasC[o] + blin[o] )
//
// Epilogue: after K-loop (Vlds dead), dump raw z to unioned Zlds[96][68]
// (2-way bank aliasing only = free per m136), barrier, band-sum via
// adjacent-row ds_read_b128, bias per-lane f4, 6 x 1KB fully-coalesced
// global_store_dwordx4 per wave (every 256-B line written whole by one wave;
// vs r12's 24x 64-B partial-line chunks assembled across 4 waves in L2).

typedef __attribute__((ext_vector_type(8))) short short8;
typedef __attribute__((ext_vector_type(8))) __bf16 bf16x8;
typedef __attribute__((ext_vector_type(4))) float f4;

#define R_ROWS 4                 // rows per block
#define VP_STRIDE 72             // 64 + 8 pad shorts
#define V_ROW_ELEMS (26 * VP_STRIDE)   // 1872 shorts (pad + 24 + pad)
#define Z_STRIDE 68              // 64 + 4 pad floats (16B-aligned rows)

__device__ __forceinline__ unsigned short f2bfu(float f) {
    return __bfloat16_as_ushort(__float2bfloat16(f));
}

// ---- Kernel 1: fold conv+linear weights -------------------------------------
// ws bytes: [0,24576) Wbig bf16[64][192]; [24576,24832) biasC f32[64];
//           [24832,25088) blinF f32[64]
__global__ void prep_kernel(const float* __restrict__ Wconv,
                            const float* __restrict__ bconv,
                            const float* __restrict__ Wlin,
                            const float* __restrict__ blin,
                            __hip_bfloat16* __restrict__ wbig,
                            float* __restrict__ biasC,
                            float* __restrict__ blinF) {
    __shared__ float Wl[4096];
    const int tid = threadIdx.x;
    for (int c = tid; c < 4096; c += 256) Wl[c] = Wlin[c];
    __syncthreads();
    int idx = blockIdx.x * 256 + tid;
    if (idx < 64 * 192) {
        int o = idx / 192;
        int j = idx - o * 192;
        int k = j >> 6;
        int i = j & 63;
        float acc = 0.0f;
        for (int c = 0; c < 64; ++c)
            acc += Wl[o * 64 + c] * Wconv[c * 192 + i * 3 + k];
        wbig[o * 192 + j] = __float2bfloat16(acc);
    } else if (idx < 64 * 192 + 64) {
        int o = idx - 64 * 192;
        float acc = 0.0f;
        for (int c = 0; c < 64; ++c)
            acc += Wl[o * 64 + c] * bconv[c];
        biasC[o] = acc;
    } else if (idx < 64 * 192 + 128) {
        int o = idx - (64 * 192 + 64);
        blinF[o] = blin[o];
    }
}

// ---- Kernel 2: fused conv-GEMM + band sum + bias + relu (full-line stores) --
__global__ __launch_bounds__(256, 6) void fused_kernel(
    const float* __restrict__ value,
    const __hip_bfloat16* __restrict__ wbig,
    const float* __restrict__ biasC,
    const float* __restrict__ blinF,
    float* __restrict__ out) {
    // Union: staging Vlds (14976 B, live until end of K-loop) and the
    // z transpose buffer Zlds (96 x 68 floats = 26112 B, live after).
    __shared__ __align__(16) float LDS[96 * Z_STRIDE];           // 26112 B
    short* const Vlds = (short*)LDS;
    float* const Zlds = LDS;

    const int tid = threadIdx.x;
    const int wave = tid >> 6;
    const int lane = tid & 63;
    const int lane15 = lane & 15;
    const int quad = lane >> 4;
    const long base_row = (long)blockIdx.x * R_ROWS;

    // ---- stage value: 4 rows x 24x64 fp32 -> bf16 padded LDS ----
    f4 pre[6];
    const int sr = tid >> 6;              // row in block 0..3 (== wave)
    const int tq = (tid >> 4) & 3;        // t mod 4 group
    const int d4 = (tid & 15) << 2;       // float4 column
    {
        const float* vrow = value + base_row * 1536 + sr * 1536 + tq * 64 + d4;
        #pragma unroll
        for (int j = 0; j < 6; ++j)
            pre[j] = *(const f4*)(vrow + j * 256);   // t = 4j+tq
    }

    // ---- B fragments for this wave's N-tile (L2-hot after block 0) ----
    const short* wsrc = (const short*)wbig;
    const int k0 = quad * 8;
    bf16x8 breg[6];
    #pragma unroll
    for (int ks = 0; ks < 6; ++ks)
        breg[ks] = __builtin_bit_cast(bf16x8,
            *(const short8*)(wsrc + (wave * 16 + lane15) * 192 + ks * 32 + k0));

    // per-lane f4 biases for the full-line epilogue (cols lane15*4 .. +3)
    const f4 bc4 = *(const f4*)(biasC + lane15 * 4);
    const f4 bl4 = *(const f4*)(blinF + lane15 * 4);
    f4 b3v, b2v;
    #pragma unroll
    for (int c = 0; c < 4; ++c) {
        b3v[c] = 3.0f * bc4[c] + bl4[c];
        b2v[c] = 2.0f * bc4[c] + bl4[c];
    }

    if (tid < 64) {                        // zero pad rows 0 and 25
        int r = tid >> 4;                  // 0..3
        int which = (tid >> 3) & 1;
        int d8 = (tid & 7) << 3;
        uint4 z; z.x = 0; z.y = 0; z.z = 0; z.w = 0;
        *(uint4*)(Vlds + r * V_ROW_ELEMS + which * (25 * VP_STRIDE) + d8) = z;
    }
    {
        short* lbase = Vlds + sr * V_ROW_ELEMS + (tq + 1) * VP_STRIDE + d4;
        #pragma unroll
        for (int j = 0; j < 6; ++j) {
            ushort4 u;
            u.x = f2bfu(pre[j].x); u.y = f2bfu(pre[j].y);
            u.z = f2bfu(pre[j].z); u.w = f2bfu(pre[j].w);
            *(ushort4*)(lbase + j * (4 * VP_STRIDE)) = u;
        }
    }
    __syncthreads();                       // barrier 1: staging visible

    // ---- K-loop: 6 M-tiles x this wave's N-tile, K=192, pure LDS+MFMA ----
    int aoff[6];
    #pragma unroll
    for (int mt = 0; mt < 6; ++mt) {
        int m = mt * 16 + lane15;          // GEMM row, m = r*24 + s
        int r = m / 24;
        int s = m - r * 24;
        aoff[mt] = r * V_ROW_ELEMS + s * VP_STRIDE;
    }
    f4 acc[6];
    #pragma unroll
    for (int mt = 0; mt < 6; ++mt) {
        f4 zz = {0.f, 0.f, 0.f, 0.f};
        acc[mt] = zz;
    }
    #pragma unroll
    for (int ks = 0; ks < 6; ++ks) {
        int k = ks * 32 + k0;
        int ka = ((k >> 6) * VP_STRIDE) + (k & 63);
        #pragma unroll
        for (int mt = 0; mt < 6; ++mt) {
            bf16x8 a = __builtin_bit_cast(bf16x8,
                *(const short8*)(Vlds + aoff[mt] + ka));
            acc[mt] = __builtin_amdgcn_mfma_f32_16x16x32_bf16(
                a, breg[ks], acc[mt], 0, 0, 0);
        }
    }
    __syncthreads();                       // barrier 2: Vlds dead -> Zlds

    // ---- dump raw z to Zlds[96][68]; z row = mt*16 + quad*4 + i, col = o ----
    // C/D layout: col = lane&15, row16 = quad*4 + i  [m89]
    {
        float* zb = Zlds + (quad * 4) * Z_STRIDE + wave * 16 + lane15;
        #pragma unroll
        for (int mt = 0; mt < 6; ++mt) {
            #pragma unroll
            for (int i = 0; i < 4; ++i)
                zb[(mt * 16 + i) * Z_STRIDE] = acc[mt][i];
        }
    }
    __syncthreads();                       // barrier 3: z visible

    // ---- band sum + bias + relu; full-line stores ----
    // wave w owns z-rows 24w..24w+23 (one full r-group: t = 0..23);
    // one store instruction = 64 lanes x 16 B = 1 KB contiguous (4 rows).
    {
        const int sub = quad;
        float* obase = out + base_row * 1536 + ((long)wave * 24) * 64
                       + lane15 * 4;
        #pragma unroll
        for (int it = 0; it < 6; ++it) {
            const int t = it * 4 + sub;            // 0..23
            const int rowL = wave * 24 + t;        // z row 0..95
            const bool att0 = (t == 0);
            const bool att23 = (t == 23);
            const int rp = att0 ? rowL : rowL - 1;
            const int rn = att23 ? rowL : rowL + 1;
            f4 zc = *(const f4*)(Zlds + rowL * Z_STRIDE + lane15 * 4);
            f4 zp = *(const f4*)(Zlds + rp * Z_STRIDE + lane15 * 4);
            f4 zn = *(const f4*)(Zlds + rn * Z_STRIDE + lane15 * 4);
            f4 s;
            #pragma unroll
            for (int c = 0; c < 4; ++c) {
                float v = zc[c];
                if (!att0)  v += zp[c];
                if (!att23) v += zn[c];
                v += (att0 || att23) ? b2v[c] : b3v[c];
                s[c] = fmaxf(v, 0.0f);
            }
            *(f4*)(obase + (it * 4 + sub) * 64) = s;
        }
    }
}

extern "C" void kernel_launch(void* const* d_in, const int* in_sizes, int n_in,
                              void* d_out, int out_size, void* d_ws, size_t ws_size,
                              hipStream_t stream) {
    const float* value = (const float*)d_in[0];
    const float* Wconv = (const float*)d_in[1];
    const float* bconv = (const float*)d_in[2];
    const float* Wlin  = (const float*)d_in[3];
    const float* blin  = (const float*)d_in[4];
    float* out = (float*)d_out;

    __hip_bfloat16* wbig = (__hip_bfloat16*)d_ws;
    float* biasC = (float*)((char*)d_ws + 24576);
    float* blinF = (float*)((char*)d_ws + 24832);

    prep_kernel<<<49, 256, 0, stream>>>(Wconv, bconv, Wlin, blin, wbig, biasC, blinF);
    // 16384 rows / 4 per block = 4096 blocks, all with full-line epilogue
    fused_kernel<<<4096, 256, 0, stream>>>(value, wbig, biasC, blinF, out);
}